// Round 1
// baseline (5939.537 us; speedup 1.0000x reference)
//
#include <hip/hip_runtime.h>
#include <hip/hip_bf16.h>
#include <stdint.h>

// Problem constants
#define B_ 8
#define H_ 512
#define F_ 256
#define P_ 12
#define M_ 4096          // B*H
#define K1_ 16384        // N*F = 64*256
#define J_ 1024          // 4*F

typedef __attribute__((ext_vector_type(8))) short short8;
typedef __attribute__((ext_vector_type(4))) float floatx4;

union FragU { uint4 u; short8 s; };

// Workspace layout (bytes)
#define OFF_W1H   ((size_t)0)          //  8,388,608  W1 swizzled bf16 hi
#define OFF_W1L   ((size_t)8388608)    //  8,388,608  W1 swizzled bf16 lo
#define OFF_WHSW  ((size_t)16777216)   //    524,288  Wh swizzled bf16
#define OFF_ENC   ((size_t)17301504)   //  4,194,304  encoder states fp32 [8][512][256]
#define OFF_C     ((size_t)21495808)   //      8,192  final c state [8][256]
#define OFF_XSUM  ((size_t)21504000)   //  4,194,304  xs transposed [256][4096]
#define OFF_XPRE  ((size_t)25698304)   // 16,777,216  Xpre [4096][1024]
#define OFF_P1    ((size_t)42475520)   // 33,554,432  split-K partials [8][256][4096]
// total ~76.0 MB

__device__ __forceinline__ unsigned short f2bf(float f) {
  uint32_t u = __float_as_uint(f);
  u += 0x7fffu + ((u >> 16) & 1u);
  return (unsigned short)(u >> 16);
}
__device__ __forceinline__ float bf2f(unsigned short h) {
  return __uint_as_float(((uint32_t)h) << 16);
}
__device__ __forceinline__ float sigm(float x) { return 1.f / (1.f + __expf(-x)); }
__device__ __forceinline__ float tanh_(float x) {
  float ax = fabsf(x);
  float e  = __expf(-2.f * ax);
  float t  = (1.f - e) / (1.f + e);
  return x < 0.f ? -t : t;
}

// ---------------------------------------------------------------------------
// Prep: W1 -> bf16 hi/lo in MFMA A-fragment swizzled layout.
// Fragment (nt, kt): lane holds A[m=lane&15][k=quad*8+j], m = W1 col, k = W1 row.
// Linear: idx = (nt*512 + kt)*64 + lane ; 16 B per lane.
__global__ void k_prep_w1(const float* __restrict__ W1,
                          uint4* __restrict__ hi, uint4* __restrict__ lo) {
  int idx  = blockIdx.x * 1024 + threadIdx.x;     // 0..524287
  int lane = idx & 63;
  int kt   = (idx >> 6) & 511;
  int nt   = idx >> 15;                            // 0..15
  int n    = nt * 16 + (lane & 15);
  int kb   = kt * 32 + ((lane >> 4) << 3);
  unsigned short h8[8], l8[8];
#pragma unroll
  for (int j = 0; j < 8; ++j) {
    float v = W1[(size_t)(kb + j) * 256 + n];
    unsigned short hh = f2bf(v);
    h8[j] = hh;
    l8[j] = f2bf(v - bf2f(hh));
  }
  uint4 uh, ul;
  uh.x = (uint32_t)h8[0] | ((uint32_t)h8[1] << 16);
  uh.y = (uint32_t)h8[2] | ((uint32_t)h8[3] << 16);
  uh.z = (uint32_t)h8[4] | ((uint32_t)h8[5] << 16);
  uh.w = (uint32_t)h8[6] | ((uint32_t)h8[7] << 16);
  ul.x = (uint32_t)l8[0] | ((uint32_t)l8[1] << 16);
  ul.y = (uint32_t)l8[2] | ((uint32_t)l8[3] << 16);
  ul.z = (uint32_t)l8[4] | ((uint32_t)l8[5] << 16);
  ul.w = (uint32_t)l8[6] | ((uint32_t)l8[7] << 16);
  hi[idx] = uh;
  lo[idx] = ul;
}

// Wh -> bf16 swizzled A-fragments. Fragment (zt, kt): m = z col, k = h index.
// Linear: idx = (zt*8 + kt)*64 + lane
__global__ void k_prep_wh(const float* __restrict__ Wh, uint4* __restrict__ sw) {
  int idx  = blockIdx.x * 1024 + threadIdx.x;     // 0..32767
  int lane = idx & 63;
  int kt   = (idx >> 6) & 7;
  int zt   = idx >> 9;                             // 0..63
  int col  = zt * 16 + (lane & 15);
  int kb   = kt * 32 + ((lane >> 4) << 3);
  unsigned short h8[8];
#pragma unroll
  for (int j = 0; j < 8; ++j) h8[j] = f2bf(Wh[(size_t)(kb + j) * 1024 + col]);
  uint4 u;
  u.x = (uint32_t)h8[0] | ((uint32_t)h8[1] << 16);
  u.y = (uint32_t)h8[2] | ((uint32_t)h8[3] << 16);
  u.z = (uint32_t)h8[4] | ((uint32_t)h8[5] << 16);
  u.w = (uint32_t)h8[6] | ((uint32_t)h8[7] << 16);
  sw[idx] = u;
}

// ---------------------------------------------------------------------------
// GEMM1 split-K: Ct[n][m] partials, n = W1 col (256), m = x row (4096).
// grid 256 = 32 row-tiles x 8 k-chunks; block 1024.
__global__ __launch_bounds__(1024)
void k_gemm1(const float* __restrict__ x, const uint4* __restrict__ w1h,
             const uint4* __restrict__ w1l, float* __restrict__ P1) {
  __shared__ __align__(16) unsigned short xh[128 * 40];
  __shared__ __align__(16) unsigned short xl[128 * 40];
  int bm = blockIdx.x >> 3, kc = blockIdx.x & 7;
  int m0 = bm * 128, kcbase = kc * 2048;
  int tid = threadIdx.x, wave = tid >> 6, lane = tid & 63;
  int quad = lane >> 4, l15 = lane & 15;
  int srow = tid >> 3, skch = tid & 7;
  floatx4 acc[8];
#pragma unroll
  for (int mt = 0; mt < 8; ++mt) acc[mt] = (floatx4)(0.f);

  for (int it = 0; it < 64; ++it) {
    int kb = kcbase + it * 32;
    const float4 xv = *(const float4*)(x + (size_t)(m0 + srow) * K1_ + kb + skch * 4);
    unsigned short h0 = f2bf(xv.x), h1 = f2bf(xv.y), h2 = f2bf(xv.z), h3 = f2bf(xv.w);
    unsigned short g0 = f2bf(xv.x - bf2f(h0)), g1 = f2bf(xv.y - bf2f(h1));
    unsigned short g2 = f2bf(xv.z - bf2f(h2)), g3 = f2bf(xv.w - bf2f(h3));
    uint2 ph, pl;
    ph.x = (uint32_t)h0 | ((uint32_t)h1 << 16); ph.y = (uint32_t)h2 | ((uint32_t)h3 << 16);
    pl.x = (uint32_t)g0 | ((uint32_t)g1 << 16); pl.y = (uint32_t)g2 | ((uint32_t)g3 << 16);
    *(uint2*)&xh[srow * 40 + skch * 4] = ph;
    *(uint2*)&xl[srow * 40 + skch * 4] = pl;
    __syncthreads();

    size_t aoff = (size_t)(wave * 512 + kc * 64 + it) * 64 + lane;
    FragU ah; ah.u = w1h[aoff];
    FragU al; al.u = w1l[aoff];
#pragma unroll
    for (int mt = 0; mt < 8; ++mt) {
      FragU bh, bl;
      bh.u = *(const uint4*)&xh[(mt * 16 + l15) * 40 + quad * 8];
      bl.u = *(const uint4*)&xl[(mt * 16 + l15) * 40 + quad * 8];
      acc[mt] = __builtin_amdgcn_mfma_f32_16x16x32_bf16(ah.s, bh.s, acc[mt], 0, 0, 0);
      acc[mt] = __builtin_amdgcn_mfma_f32_16x16x32_bf16(ah.s, bl.s, acc[mt], 0, 0, 0);
      acc[mt] = __builtin_amdgcn_mfma_f32_16x16x32_bf16(al.s, bh.s, acc[mt], 0, 0, 0);
    }
    __syncthreads();
  }
  int nbase = wave * 16 + quad * 4;
#pragma unroll
  for (int mt = 0; mt < 8; ++mt) {
    int m = m0 + mt * 16 + l15;
#pragma unroll
    for (int r = 0; r < 4; ++r)
      P1[(size_t)(kc * 256 + nbase + r) * M_ + m] = acc[mt][r];
  }
}

// Sum split-K partials + b1 -> xsum[k][m] (k = feature 0..255)
__global__ void k_reduce(const float* __restrict__ P1, const float* __restrict__ b1,
                         float* __restrict__ xsum) {
  int idx = blockIdx.x * 1024 + threadIdx.x;       // 1,048,576
  int k = idx >> 12, m = idx & 4095;
  float s = b1[k];
#pragma unroll
  for (int kc = 0; kc < 8; ++kc) s += P1[(size_t)(kc * 256 + k) * M_ + m];
  xsum[(size_t)k * M_ + m] = s;
}

// GEMM2 (fp32 VALU, full precision): Xpre[m][col] = b[col] + sum_k xs[m][k]*Wx[k][col]
// grid 256 blocks x 256 threads; each block does 16 m rows.
__global__ __launch_bounds__(256)
void k_gemm2(const float* __restrict__ xsum, const float* __restrict__ Wx,
             const float* __restrict__ bz, float* __restrict__ Xpre) {
  int m0 = blockIdx.x * 16;
  int j = threadIdx.x;
  float acc0[16], acc1[16], acc2[16], acc3[16];
  float bb0 = bz[j], bb1 = bz[256 + j], bb2 = bz[512 + j], bb3 = bz[768 + j];
#pragma unroll
  for (int mm = 0; mm < 16; ++mm) { acc0[mm] = bb0; acc1[mm] = bb1; acc2[mm] = bb2; acc3[mm] = bb3; }
  for (int k = 0; k < 256; ++k) {
    float w0 = Wx[(size_t)k * 1024 + j];
    float w1 = Wx[(size_t)k * 1024 + 256 + j];
    float w2 = Wx[(size_t)k * 1024 + 512 + j];
    float w3 = Wx[(size_t)k * 1024 + 768 + j];
#pragma unroll
    for (int mm = 0; mm < 16; ++mm) {
      float xv = xsum[(size_t)k * M_ + m0 + mm];
      acc0[mm] += xv * w0; acc1[mm] += xv * w1; acc2[mm] += xv * w2; acc3[mm] += xv * w3;
    }
  }
#pragma unroll
  for (int mm = 0; mm < 16; ++mm) {
    float* o = Xpre + (size_t)(m0 + mm) * 1024;
    o[j] = acc0[mm]; o[256 + j] = acc1[mm]; o[512 + j] = acc2[mm]; o[768 + j] = acc3[mm];
  }
}

// ---------------------------------------------------------------------------
// Encoder: one block per batch, 512 sequential LSTM steps.
// z^T = Wh^T (A, streamed swizzled frags) x h (B, broadcast bf16 hi+lo from LDS)
__global__ __launch_bounds__(512)
void k_encoder(const uint4* __restrict__ whsw, const float* __restrict__ Xpre,
               float* __restrict__ enc, float* __restrict__ cws) {
  __shared__ __align__(16) unsigned short hbh[256];
  __shared__ __align__(16) unsigned short hbl[256];
  __shared__ __align__(16) float z[1024];
  __shared__ float c[256];
  int b = blockIdx.x, tid = threadIdx.x;
  int wave = tid >> 6, lane = tid & 63;
  int quad = lane >> 4, l15 = lane & 15;
  if (tid < 256) { hbh[tid] = 0; hbl[tid] = 0; c[tid] = 0.f; }
  __syncthreads();
  const float* xpb = Xpre + (size_t)b * 512 * 1024;
  int zt0 = wave * 8;

  for (int t = 0; t < 512; ++t) {
    // B fragments: broadcast h (all 16 cols identical -> all output cols equal z)
    FragU bh[8], bl[8];
#pragma unroll
    for (int kt = 0; kt < 8; ++kt) {
      bh[kt].u = *(const uint4*)((const char*)hbh + kt * 64 + (quad << 4));
      bl[kt].u = *(const uint4*)((const char*)hbl + kt * 64 + (quad << 4));
    }
    const float* xp = xpb + (size_t)t * 1024;
    uint4 afr[2][8];
#pragma unroll
    for (int kt = 0; kt < 8; ++kt) afr[0][kt] = whsw[(size_t)((zt0 * 8 + kt) * 64 + lane)];
    for (int q = 0; q < 8; ++q) {
      int cur = q & 1;
      int zt = zt0 + q;
      if (q < 7) {
#pragma unroll
        for (int kt = 0; kt < 8; ++kt)
          afr[cur ^ 1][kt] = whsw[(size_t)(((zt + 1) * 8 + kt) * 64 + lane)];
      }
      floatx4 acc = *(const floatx4*)(xp + zt * 16 + quad * 4);  // Xpre init (has bias b)
#pragma unroll
      for (int kt = 0; kt < 8; ++kt) {
        FragU a; a.u = afr[cur][kt];
        acc = __builtin_amdgcn_mfma_f32_16x16x32_bf16(a.s, bh[kt].s, acc, 0, 0, 0);
        acc = __builtin_amdgcn_mfma_f32_16x16x32_bf16(a.s, bl[kt].s, acc, 0, 0, 0);
      }
      if (l15 == 0) *(floatx4*)&z[zt * 16 + quad * 4] = acc;  // col 0 holds z
    }
    __syncthreads();
    if (tid < 256) {
      float zi = z[tid], zf = z[256 + tid], zg = z[512 + tid], zo = z[768 + tid];
      float ig = sigm(zi), fg = sigm(zf), gg = tanh_(zg), og = sigm(zo);
      float cn = fg * c[tid] + ig * gg;
      c[tid] = cn;
      float hn = og * tanh_(cn);
      enc[((size_t)b * 512 + t) * 256 + tid] = hn;
      unsigned short hh = f2bf(hn);
      hbh[tid] = hh;
      hbl[tid] = f2bf(hn - bf2f(hh));
    }
    __syncthreads();
  }
  if (tid < 256) cws[b * 256 + tid] = c[tid];
}

// ---------------------------------------------------------------------------
// Decoder: one block per batch, 12 steps, attention + LSTM cell, fp32 VALU.
__global__ __launch_bounds__(1024)
void k_decoder(const float* __restrict__ enc, const float* __restrict__ cws,
               const float* __restrict__ Wx, const float* __restrict__ Wh,
               const float* __restrict__ bz, const float* __restrict__ Wa,
               const float* __restrict__ ba, const float* __restrict__ W2,
               const float* __restrict__ b2, float* __restrict__ out) {
  __shared__ float h[256], c[256], q[256], ctx[256];
  __shared__ float sc[512];
  __shared__ float zb[1024];
  __shared__ float smx[2];
  int b = blockIdx.x, tid = threadIdx.x;
  int wave = tid >> 6, lane = tid & 63;
  const float* encb = enc + (size_t)b * 512 * 256;
  if (tid < 256) { h[tid] = encb[(size_t)511 * 256 + tid]; c[tid] = cws[b * 256 + tid]; }
  __syncthreads();

  for (int p = 0; p < 12; ++p) {
    // q = h @ Wa + ba
    {
      int j = tid & 255, ks = tid >> 8;
      float s = 0.f;
      for (int kk = 0; kk < 64; ++kk) {
        int k = ks * 64 + kk;
        s += h[k] * Wa[(size_t)k * 256 + j];
      }
      zb[tid] = s;
    }
    __syncthreads();
    if (tid < 256) q[tid] = ba[tid] + zb[tid] + zb[256 + tid] + zb[512 + tid] + zb[768 + tid];
    __syncthreads();
    // scores: one wave per group of 32 rows, lane-parallel over k
    {
      float4 qv = *(const float4*)&q[lane * 4];
      for (int r = 0; r < 32; ++r) {
        int hh = wave * 32 + r;
        const float4 ev = *(const float4*)(encb + (size_t)hh * 256 + lane * 4);
        float s = ev.x * qv.x + ev.y * qv.y + ev.z * qv.z + ev.w * qv.w;
#pragma unroll
        for (int off = 32; off >= 1; off >>= 1) s += __shfl_xor(s, off, 64);
        if (lane == 0) sc[hh] = s;
      }
    }
    __syncthreads();
    if (tid < 64) {
      float m = -3.4e38f;
      for (int r = 0; r < 8; ++r) m = fmaxf(m, sc[tid * 8 + r]);
#pragma unroll
      for (int off = 32; off >= 1; off >>= 1) m = fmaxf(m, __shfl_xor(m, off, 64));
      if (tid == 0) smx[0] = m;
    }
    __syncthreads();
    if (tid < 512) sc[tid] = __expf(sc[tid] - smx[0]);
    __syncthreads();
    if (tid < 64) {
      float s = 0.f;
      for (int r = 0; r < 8; ++r) s += sc[tid * 8 + r];
#pragma unroll
      for (int off = 32; off >= 1; off >>= 1) s += __shfl_xor(s, off, 64);
      if (tid == 0) smx[1] = 1.f / s;
    }
    __syncthreads();
    // ctx = softmax(sc) @ enc
    {
      int k = tid & 255, hs = tid >> 8;
      float s = 0.f;
      for (int r = 0; r < 128; ++r) {
        int hh = hs * 128 + r;
        s += sc[hh] * encb[(size_t)hh * 256 + k];
      }
      zb[tid] = s;
    }
    __syncthreads();
    if (tid < 256) ctx[tid] = (zb[tid] + zb[256 + tid] + zb[512 + tid] + zb[768 + tid]) * smx[1];
    __syncthreads();
    // cell: z = b + ctx@Wx + h@Wh (fp32)
    {
      float s = bz[tid];
      for (int k = 0; k < 256; ++k) {
        s += ctx[k] * Wx[(size_t)k * 1024 + tid] + h[k] * Wh[(size_t)k * 1024 + tid];
      }
      zb[tid] = s;
    }
    __syncthreads();
    if (tid < 256) {
      float zi = zb[tid], zf = zb[256 + tid], zg = zb[512 + tid], zo = zb[768 + tid];
      float ig = sigm(zi), fg = sigm(zf), gg = tanh_(zg), og = sigm(zo);
      float cn = fg * c[tid] + ig * gg;
      c[tid] = cn;
      h[tid] = og * tanh_(cn);
    }
    __syncthreads();
    if (tid < 64) {
      float s = b2[tid];
      for (int f = 0; f < 256; ++f) s += h[f] * W2[(size_t)f * 64 + tid];
      out[((size_t)b * 12 + p) * 64 + tid] = s;
    }
    __syncthreads();
  }
}

// ---------------------------------------------------------------------------
extern "C" void kernel_launch(void* const* d_in, const int* in_sizes, int n_in,
                              void* d_out, int out_size, void* d_ws, size_t ws_size,
                              hipStream_t stream) {
  const float* x  = (const float*)d_in[0];
  const float* W1 = (const float*)d_in[1];
  const float* b1 = (const float*)d_in[2];
  const float* Wx = (const float*)d_in[3];
  const float* Wh = (const float*)d_in[4];
  const float* bz = (const float*)d_in[5];
  const float* Wa = (const float*)d_in[6];
  const float* ba = (const float*)d_in[7];
  const float* W2 = (const float*)d_in[8];
  const float* b2 = (const float*)d_in[9];

  char* ws = (char*)d_ws;
  uint4* w1h  = (uint4*)(ws + OFF_W1H);
  uint4* w1l  = (uint4*)(ws + OFF_W1L);
  uint4* whsw = (uint4*)(ws + OFF_WHSW);
  float* enc  = (float*)(ws + OFF_ENC);
  float* cws  = (float*)(ws + OFF_C);
  float* xsum = (float*)(ws + OFF_XSUM);
  float* xpre = (float*)(ws + OFF_XPRE);
  float* p1   = (float*)(ws + OFF_P1);

  k_prep_w1<<<dim3(512), dim3(1024), 0, stream>>>(W1, w1h, w1l);
  k_prep_wh<<<dim3(32), dim3(1024), 0, stream>>>(Wh, whsw);
  k_gemm1<<<dim3(256), dim3(1024), 0, stream>>>(x, w1h, w1l, p1);
  k_reduce<<<dim3(1024), dim3(1024), 0, stream>>>(p1, b1, xsum);
  k_gemm2<<<dim3(256), dim3(256), 0, stream>>>(xsum, Wx, bz, xpre);
  k_encoder<<<dim3(8), dim3(512), 0, stream>>>(whsw, xpre, enc, cws);
  k_decoder<<<dim3(8), dim3(1024), 0, stream>>>(enc, cws, Wx, Wh, bz, Wa, ba, W2, b2,
                                                (float*)d_out);
}

// Round 2
// 3206.093 us; speedup vs baseline: 1.8526x; 1.8526x over previous
//
#include <hip/hip_runtime.h>
#include <hip/hip_bf16.h>
#include <stdint.h>

// Problem constants
#define B_ 8
#define H_ 512
#define F_ 256
#define P_ 12
#define M_ 4096          // B*H
#define K1_ 16384        // N*F = 64*256
#define J_ 1024          // 4*F

typedef __attribute__((ext_vector_type(8))) short short8;
typedef __attribute__((ext_vector_type(4))) float floatx4;

union FragU { uint4 u; short8 s; };

// Workspace layout (bytes)
#define OFF_W1H   ((size_t)0)          //  8,388,608  W1 swizzled bf16 hi
#define OFF_W1L   ((size_t)8388608)    //  8,388,608  W1 swizzled bf16 lo
#define OFF_WHSW  ((size_t)16777216)   //    524,288  Wh swizzled bf16
#define OFF_ENC   ((size_t)17301504)   //  4,194,304  encoder states fp32 [8][512][256]
#define OFF_C     ((size_t)21495808)   //      8,192  final c state [8][256]
#define OFF_XSUM  ((size_t)21504000)   //  4,194,304  xs transposed [256][4096]
#define OFF_XPRE  ((size_t)25698304)   // 16,777,216  Xpre [4096][1024]
#define OFF_P1    ((size_t)42475520)   // 33,554,432  split-K partials [8][256][4096]
// total ~76.0 MB

__device__ __forceinline__ unsigned short f2bf(float f) {
  uint32_t u = __float_as_uint(f);
  u += 0x7fffu + ((u >> 16) & 1u);
  return (unsigned short)(u >> 16);
}
__device__ __forceinline__ float bf2f(unsigned short h) {
  return __uint_as_float(((uint32_t)h) << 16);
}
__device__ __forceinline__ float sigm(float x) { return 1.f / (1.f + __expf(-x)); }
__device__ __forceinline__ float tanh_(float x) {
  float ax = fabsf(x);
  float e  = __expf(-2.f * ax);
  float t  = (1.f - e) / (1.f + e);
  return x < 0.f ? -t : t;
}

// ---------------------------------------------------------------------------
// Prep: W1 -> bf16 hi/lo in MFMA A-fragment swizzled layout.
__global__ void k_prep_w1(const float* __restrict__ W1,
                          uint4* __restrict__ hi, uint4* __restrict__ lo) {
  int idx  = blockIdx.x * 1024 + threadIdx.x;     // 0..524287
  int lane = idx & 63;
  int kt   = (idx >> 6) & 511;
  int nt   = idx >> 15;                            // 0..15
  int n    = nt * 16 + (lane & 15);
  int kb   = kt * 32 + ((lane >> 4) << 3);
  unsigned short h8[8], l8[8];
#pragma unroll
  for (int j = 0; j < 8; ++j) {
    float v = W1[(size_t)(kb + j) * 256 + n];
    unsigned short hh = f2bf(v);
    h8[j] = hh;
    l8[j] = f2bf(v - bf2f(hh));
  }
  uint4 uh, ul;
  uh.x = (uint32_t)h8[0] | ((uint32_t)h8[1] << 16);
  uh.y = (uint32_t)h8[2] | ((uint32_t)h8[3] << 16);
  uh.z = (uint32_t)h8[4] | ((uint32_t)h8[5] << 16);
  uh.w = (uint32_t)h8[6] | ((uint32_t)h8[7] << 16);
  ul.x = (uint32_t)l8[0] | ((uint32_t)l8[1] << 16);
  ul.y = (uint32_t)l8[2] | ((uint32_t)l8[3] << 16);
  ul.z = (uint32_t)l8[4] | ((uint32_t)l8[5] << 16);
  ul.w = (uint32_t)l8[6] | ((uint32_t)l8[7] << 16);
  hi[idx] = uh;
  lo[idx] = ul;
}

// Wh -> bf16 swizzled A-fragments. Fragment (zt, kt): m = z col, k = h index.
// Linear: idx = (zt*8 + kt)*64 + lane
__global__ void k_prep_wh(const float* __restrict__ Wh, uint4* __restrict__ sw) {
  int idx  = blockIdx.x * 1024 + threadIdx.x;     // 0..32767
  int lane = idx & 63;
  int kt   = (idx >> 6) & 7;
  int zt   = idx >> 9;                             // 0..63
  int col  = zt * 16 + (lane & 15);
  int kb   = kt * 32 + ((lane >> 4) << 3);
  unsigned short h8[8];
#pragma unroll
  for (int j = 0; j < 8; ++j) h8[j] = f2bf(Wh[(size_t)(kb + j) * 1024 + col]);
  uint4 u;
  u.x = (uint32_t)h8[0] | ((uint32_t)h8[1] << 16);
  u.y = (uint32_t)h8[2] | ((uint32_t)h8[3] << 16);
  u.z = (uint32_t)h8[4] | ((uint32_t)h8[5] << 16);
  u.w = (uint32_t)h8[6] | ((uint32_t)h8[7] << 16);
  sw[idx] = u;
}

// ---------------------------------------------------------------------------
// GEMM1 split-K (unchanged from round 1)
__global__ __launch_bounds__(1024)
void k_gemm1(const float* __restrict__ x, const uint4* __restrict__ w1h,
             const uint4* __restrict__ w1l, float* __restrict__ P1) {
  __shared__ __align__(16) unsigned short xh[128 * 40];
  __shared__ __align__(16) unsigned short xl[128 * 40];
  int bm = blockIdx.x >> 3, kc = blockIdx.x & 7;
  int m0 = bm * 128, kcbase = kc * 2048;
  int tid = threadIdx.x, wave = tid >> 6, lane = tid & 63;
  int quad = lane >> 4, l15 = lane & 15;
  int srow = tid >> 3, skch = tid & 7;
  floatx4 acc[8];
#pragma unroll
  for (int mt = 0; mt < 8; ++mt) acc[mt] = (floatx4)(0.f);

  for (int it = 0; it < 64; ++it) {
    int kb = kcbase + it * 32;
    const float4 xv = *(const float4*)(x + (size_t)(m0 + srow) * K1_ + kb + skch * 4);
    unsigned short h0 = f2bf(xv.x), h1 = f2bf(xv.y), h2 = f2bf(xv.z), h3 = f2bf(xv.w);
    unsigned short g0 = f2bf(xv.x - bf2f(h0)), g1 = f2bf(xv.y - bf2f(h1));
    unsigned short g2 = f2bf(xv.z - bf2f(h2)), g3 = f2bf(xv.w - bf2f(h3));
    uint2 ph, pl;
    ph.x = (uint32_t)h0 | ((uint32_t)h1 << 16); ph.y = (uint32_t)h2 | ((uint32_t)h3 << 16);
    pl.x = (uint32_t)g0 | ((uint32_t)g1 << 16); pl.y = (uint32_t)g2 | ((uint32_t)g3 << 16);
    *(uint2*)&xh[srow * 40 + skch * 4] = ph;
    *(uint2*)&xl[srow * 40 + skch * 4] = pl;
    __syncthreads();

    size_t aoff = (size_t)(wave * 512 + kc * 64 + it) * 64 + lane;
    FragU ah; ah.u = w1h[aoff];
    FragU al; al.u = w1l[aoff];
#pragma unroll
    for (int mt = 0; mt < 8; ++mt) {
      FragU bh, bl;
      bh.u = *(const uint4*)&xh[(mt * 16 + l15) * 40 + quad * 8];
      bl.u = *(const uint4*)&xl[(mt * 16 + l15) * 40 + quad * 8];
      acc[mt] = __builtin_amdgcn_mfma_f32_16x16x32_bf16(ah.s, bh.s, acc[mt], 0, 0, 0);
      acc[mt] = __builtin_amdgcn_mfma_f32_16x16x32_bf16(ah.s, bl.s, acc[mt], 0, 0, 0);
      acc[mt] = __builtin_amdgcn_mfma_f32_16x16x32_bf16(al.s, bh.s, acc[mt], 0, 0, 0);
    }
    __syncthreads();
  }
  int nbase = wave * 16 + quad * 4;
#pragma unroll
  for (int mt = 0; mt < 8; ++mt) {
    int m = m0 + mt * 16 + l15;
#pragma unroll
    for (int r = 0; r < 4; ++r)
      P1[(size_t)(kc * 256 + nbase + r) * M_ + m] = acc[mt][r];
  }
}

// Sum split-K partials + b1 -> xsum[k][m]
__global__ void k_reduce(const float* __restrict__ P1, const float* __restrict__ b1,
                         float* __restrict__ xsum) {
  int idx = blockIdx.x * 1024 + threadIdx.x;       // 1,048,576
  int k = idx >> 12, m = idx & 4095;
  float s = b1[k];
#pragma unroll
  for (int kc = 0; kc < 8; ++kc) s += P1[(size_t)(kc * 256 + k) * M_ + m];
  xsum[(size_t)k * M_ + m] = s;
}

// GEMM2 (fp32 VALU, unchanged)
__global__ __launch_bounds__(256)
void k_gemm2(const float* __restrict__ xsum, const float* __restrict__ Wx,
             const float* __restrict__ bz, float* __restrict__ Xpre) {
  int m0 = blockIdx.x * 16;
  int j = threadIdx.x;
  float acc0[16], acc1[16], acc2[16], acc3[16];
  float bb0 = bz[j], bb1 = bz[256 + j], bb2 = bz[512 + j], bb3 = bz[768 + j];
#pragma unroll
  for (int mm = 0; mm < 16; ++mm) { acc0[mm] = bb0; acc1[mm] = bb1; acc2[mm] = bb2; acc3[mm] = bb3; }
  for (int k = 0; k < 256; ++k) {
    float w0 = Wx[(size_t)k * 1024 + j];
    float w1 = Wx[(size_t)k * 1024 + 256 + j];
    float w2 = Wx[(size_t)k * 1024 + 512 + j];
    float w3 = Wx[(size_t)k * 1024 + 768 + j];
#pragma unroll
    for (int mm = 0; mm < 16; ++mm) {
      float xv = xsum[(size_t)k * M_ + m0 + mm];
      acc0[mm] += xv * w0; acc1[mm] += xv * w1; acc2[mm] += xv * w2; acc3[mm] += xv * w3;
    }
  }
#pragma unroll
  for (int mm = 0; mm < 16; ++mm) {
    float* o = Xpre + (size_t)(m0 + mm) * 1024;
    o[j] = acc0[mm]; o[256 + j] = acc1[mm]; o[512 + j] = acc2[mm]; o[768 + j] = acc3[mm];
  }
}

// ---------------------------------------------------------------------------
// Encoder v2: one 256-thread block per batch; Wh fully resident:
//   - 96 frags/wave in VGPRs (384 regs), 32 frags/wave in LDS (128 KB).
//   - B-column trick: h_hi in MFMA B col 0, h_lo in col 1 -> one MFMA pass.
//   - z = z0(col0) + z1(col1) + Xpre(prefetched regs) in the gate phase.
#define ENC_MFMA_BODY(ASRC, ZT)                                                \
  {                                                                            \
    floatx4 acc = (floatx4)(0.f);                                              \
    FragU a_;                                                                  \
    _Pragma("unroll")                                                          \
    for (int kt = 0; kt < 8; ++kt) {                                           \
      a_.u = (ASRC);                                                           \
      acc = __builtin_amdgcn_mfma_f32_16x16x32_bf16(a_.s, bf[kt].s, acc, 0, 0, 0); \
    }                                                                          \
    if (l15 == 0)      *(floatx4*)&z0[(ZT) * 16 + quad * 4] = acc;             \
    else if (l15 == 1) *(floatx4*)&z1[(ZT) * 16 + quad * 4] = acc;             \
  }

#define ENC_REG(i)  ENC_MFMA_BODY(wfr[(i) * 8 + kt], wave * 16 + (i))
#define ENC_PF(i2)  ENC_MFMA_BODY(pf[kt], wave * 16 + 12 + (i2))
#define ENC_PFLOAD(i2)                                                         \
  {                                                                            \
    _Pragma("unroll")                                                          \
    for (int kt = 0; kt < 8; ++kt)                                             \
      pf[kt] = wl[((wave * 4 + (i2)) * 8 + kt) * 64 + lane];                   \
  }

__global__ __launch_bounds__(256, 1)
void k_encoder(const uint4* __restrict__ whsw, const float* __restrict__ Xpre,
               float* __restrict__ enc, float* __restrict__ cws) {
  __shared__ uint4 wl[8192];                         // 128 KB LDS-resident Wh frags
  __shared__ __align__(16) unsigned short hb[512];   // [0..255]=h hi, [256..511]=h lo
  __shared__ __align__(16) float z0[1024], z1[1024];
  __shared__ float c[256];
  int b = blockIdx.x, tid = threadIdx.x;
  int wave = tid >> 6, lane = tid & 63;
  int quad = lane >> 4, l15 = lane & 15;

  // stage LDS-resident weight frags (zt local i = 12..15 of each wave's 16)
  {
    int grp = tid >> 6;
    for (int rep = 0; rep < 32; ++rep) {
      int s = rep * 4 + grp;                 // 0..127
      int w = s >> 5, i2 = (s >> 3) & 3, kt = s & 7;
      wl[s * 64 + lane] = whsw[(size_t)(((w * 16 + 12 + i2) * 8 + kt) * 64 + lane)];
    }
  }
  // register-resident frags: zt local i = 0..11
  uint4 wfr[96];
#pragma unroll
  for (int i = 0; i < 12; ++i)
#pragma unroll
    for (int kt = 0; kt < 8; ++kt)
      wfr[i * 8 + kt] = whsw[(size_t)(((wave * 16 + i) * 8 + kt) * 64 + lane)];

  hb[tid] = 0; hb[256 + tid] = 0; c[tid] = 0.f;
  const float* xpb = Xpre + (size_t)b * 512 * 1024;
  float xq0 = xpb[tid], xq1 = xpb[256 + tid], xq2 = xpb[512 + tid], xq3 = xpb[768 + tid];
  int hoff = ((l15 == 1) ? 256 : 0) + quad * 8;
  __syncthreads();

  for (int t = 0; t < 512; ++t) {
    // B frags: col0 = h_hi, col1 = h_lo, cols>=2 read hi (ignored)
    FragU bf[8];
#pragma unroll
    for (int kt = 0; kt < 8; ++kt)
      bf[kt].u = *(const uint4*)&hb[hoff + kt * 32];
    // prefetch next Xpre row
    float nx0, nx1, nx2, nx3;
    if (t < 511) {
      const float* xp = xpb + (size_t)(t + 1) * 1024;
      nx0 = xp[tid]; nx1 = xp[256 + tid]; nx2 = xp[512 + tid]; nx3 = xp[768 + tid];
    } else { nx0 = nx1 = nx2 = nx3 = 0.f; }

    uint4 pf[8];
    ENC_PFLOAD(0);
    ENC_REG(0); ENC_REG(1); ENC_REG(2);
    ENC_PF(0);  ENC_PFLOAD(1);
    ENC_REG(3); ENC_REG(4); ENC_REG(5);
    ENC_PF(1);  ENC_PFLOAD(2);
    ENC_REG(6); ENC_REG(7); ENC_REG(8);
    ENC_PF(2);  ENC_PFLOAD(3);
    ENC_REG(9); ENC_REG(10); ENC_REG(11);
    ENC_PF(3);
    __syncthreads();

    // gates (all 256 threads)
    float zi = z0[tid] + z1[tid] + xq0;
    float zf = z0[256 + tid] + z1[256 + tid] + xq1;
    float zg = z0[512 + tid] + z1[512 + tid] + xq2;
    float zo = z0[768 + tid] + z1[768 + tid] + xq3;
    float ig = sigm(zi), fg = sigm(zf), gg = tanh_(zg), og = sigm(zo);
    float cn = fg * c[tid] + ig * gg;
    c[tid] = cn;
    float hn = og * tanh_(cn);
    enc[((size_t)b * 512 + t) * 256 + tid] = hn;
    unsigned short hh = f2bf(hn);
    hb[tid] = hh;
    hb[256 + tid] = f2bf(hn - bf2f(hh));
    __syncthreads();
    xq0 = nx0; xq1 = nx1; xq2 = nx2; xq3 = nx3;
  }
  cws[b * 256 + tid] = c[tid];
}

// ---------------------------------------------------------------------------
// Decoder (unchanged from round 1)
__global__ __launch_bounds__(1024)
void k_decoder(const float* __restrict__ enc, const float* __restrict__ cws,
               const float* __restrict__ Wx, const float* __restrict__ Wh,
               const float* __restrict__ bz, const float* __restrict__ Wa,
               const float* __restrict__ ba, const float* __restrict__ W2,
               const float* __restrict__ b2, float* __restrict__ out) {
  __shared__ float h[256], c[256], q[256], ctx[256];
  __shared__ float sc[512];
  __shared__ float zb[1024];
  __shared__ float smx[2];
  int b = blockIdx.x, tid = threadIdx.x;
  int wave = tid >> 6, lane = tid & 63;
  const float* encb = enc + (size_t)b * 512 * 256;
  if (tid < 256) { h[tid] = encb[(size_t)511 * 256 + tid]; c[tid] = cws[b * 256 + tid]; }
  __syncthreads();

  for (int p = 0; p < 12; ++p) {
    {
      int j = tid & 255, ks = tid >> 8;
      float s = 0.f;
      for (int kk = 0; kk < 64; ++kk) {
        int k = ks * 64 + kk;
        s += h[k] * Wa[(size_t)k * 256 + j];
      }
      zb[tid] = s;
    }
    __syncthreads();
    if (tid < 256) q[tid] = ba[tid] + zb[tid] + zb[256 + tid] + zb[512 + tid] + zb[768 + tid];
    __syncthreads();
    {
      float4 qv = *(const float4*)&q[lane * 4];
      for (int r = 0; r < 32; ++r) {
        int hh = wave * 32 + r;
        const float4 ev = *(const float4*)(encb + (size_t)hh * 256 + lane * 4);
        float s = ev.x * qv.x + ev.y * qv.y + ev.z * qv.z + ev.w * qv.w;
#pragma unroll
        for (int off = 32; off >= 1; off >>= 1) s += __shfl_xor(s, off, 64);
        if (lane == 0) sc[hh] = s;
      }
    }
    __syncthreads();
    if (tid < 64) {
      float m = -3.4e38f;
      for (int r = 0; r < 8; ++r) m = fmaxf(m, sc[tid * 8 + r]);
#pragma unroll
      for (int off = 32; off >= 1; off >>= 1) m = fmaxf(m, __shfl_xor(m, off, 64));
      if (tid == 0) smx[0] = m;
    }
    __syncthreads();
    if (tid < 512) sc[tid] = __expf(sc[tid] - smx[0]);
    __syncthreads();
    if (tid < 64) {
      float s = 0.f;
      for (int r = 0; r < 8; ++r) s += sc[tid * 8 + r];
#pragma unroll
      for (int off = 32; off >= 1; off >>= 1) s += __shfl_xor(s, off, 64);
      if (tid == 0) smx[1] = 1.f / s;
    }
    __syncthreads();
    {
      int k = tid & 255, hs = tid >> 8;
      float s = 0.f;
      for (int r = 0; r < 128; ++r) {
        int hh = hs * 128 + r;
        s += sc[hh] * encb[(size_t)hh * 256 + k];
      }
      zb[tid] = s;
    }
    __syncthreads();
    if (tid < 256) ctx[tid] = (zb[tid] + zb[256 + tid] + zb[512 + tid] + zb[768 + tid]) * smx[1];
    __syncthreads();
    {
      float s = bz[tid];
      for (int k = 0; k < 256; ++k) {
        s += ctx[k] * Wx[(size_t)k * 1024 + tid] + h[k] * Wh[(size_t)k * 1024 + tid];
      }
      zb[tid] = s;
    }
    __syncthreads();
    if (tid < 256) {
      float zi = zb[tid], zf = zb[256 + tid], zg = zb[512 + tid], zo = zb[768 + tid];
      float ig = sigm(zi), fg = sigm(zf), gg = tanh_(zg), og = sigm(zo);
      float cn = fg * c[tid] + ig * gg;
      c[tid] = cn;
      h[tid] = og * tanh_(cn);
    }
    __syncthreads();
    if (tid < 64) {
      float s = b2[tid];
      for (int f = 0; f < 256; ++f) s += h[f] * W2[(size_t)f * 64 + tid];
      out[((size_t)b * 12 + p) * 64 + tid] = s;
    }
    __syncthreads();
  }
}

// ---------------------------------------------------------------------------
extern "C" void kernel_launch(void* const* d_in, const int* in_sizes, int n_in,
                              void* d_out, int out_size, void* d_ws, size_t ws_size,
                              hipStream_t stream) {
  const float* x  = (const float*)d_in[0];
  const float* W1 = (const float*)d_in[1];
  const float* b1 = (const float*)d_in[2];
  const float* Wx = (const float*)d_in[3];
  const float* Wh = (const float*)d_in[4];
  const float* bz = (const float*)d_in[5];
  const float* Wa = (const float*)d_in[6];
  const float* ba = (const float*)d_in[7];
  const float* W2 = (const float*)d_in[8];
  const float* b2 = (const float*)d_in[9];

  char* ws = (char*)d_ws;
  uint4* w1h  = (uint4*)(ws + OFF_W1H);
  uint4* w1l  = (uint4*)(ws + OFF_W1L);
  uint4* whsw = (uint4*)(ws + OFF_WHSW);
  float* enc  = (float*)(ws + OFF_ENC);
  float* cws  = (float*)(ws + OFF_C);
  float* xsum = (float*)(ws + OFF_XSUM);
  float* xpre = (float*)(ws + OFF_XPRE);
  float* p1   = (float*)(ws + OFF_P1);

  k_prep_w1<<<dim3(512), dim3(1024), 0, stream>>>(W1, w1h, w1l);
  k_prep_wh<<<dim3(32), dim3(1024), 0, stream>>>(Wh, whsw);
  k_gemm1<<<dim3(256), dim3(1024), 0, stream>>>(x, w1h, w1l, p1);
  k_reduce<<<dim3(1024), dim3(1024), 0, stream>>>(p1, b1, xsum);
  k_gemm2<<<dim3(256), dim3(256), 0, stream>>>(xsum, Wx, bz, xpre);
  k_encoder<<<dim3(8), dim3(256), 0, stream>>>(whsw, xpre, enc, cws);
  k_decoder<<<dim3(8), dim3(1024), 0, stream>>>(enc, cws, Wx, Wh, bz, Wa, ba, W2, b2,
                                                (float*)d_out);
}